// Round 9
// baseline (5696.220 us; speedup 1.0000x reference)
//
#include <hip/hip_runtime.h>

typedef _Float16 half8 __attribute__((ext_vector_type(8)));
typedef _Float16 f16x2 __attribute__((ext_vector_type(2)));
typedef _Float16 f16x4 __attribute__((ext_vector_type(4)));
typedef float floatx4 __attribute__((ext_vector_type(4)));

#define NB 256    // batch
#define NT 512    // time
#define NI 64     // input
#define NH 256    // hidden
#define NSEQ 16   // sequences per group
#define QB 4      // hidden quarters (blocks per group)
#define NGRP (NB / NSEQ)     // 16 groups
#define NBLK (NGRP * QB)     // 64 blocks, 1 CU each
#define THR 256              // 4 waves
#define HS 344               // H row stride in f16 (validated bank pattern)

// B-fragment pack (VALIDATED R9/R10): 480 frags x 64 lanes x 8 f16.
// Cols: [0,256)=r, [256,512)=z, [512,768)=h_n, [768,1024)=i_n. K: [0,256)=h, [256,320)=x.
// frag f: r: tt*10+kb; z: 160+tt*10+kb; h_n: 320+tt*8+kb (kb<8); i_n: 448+tt*2+(kb-8).
// wb[f*512 + lane*8 + i] = W[k = kb*32 + (lane>>4)*8 + i][n = tt*16 + (lane&15)]
#define WB_N (480 * 512)
#define HD_N ((size_t)NT * NB * NH)
#define HX_N ((size_t)2 * NB * NH)   // parity-double-buffered h exchange (f16)

__global__ __launch_bounds__(256) void gru_prep_kernel(
    const float* __restrict__ w_ih, const float* __restrict__ w_hh,
    _Float16* __restrict__ wb, int* __restrict__ flags)
{
  if (blockIdx.x == 0 && threadIdx.x < NBLK) flags[threadIdx.x] = 0;  // reset handshake
  int n = blockIdx.x * 256 + threadIdx.x;
  if (n >= WB_N) return;
  int i = n & 7, l = (n >> 3) & 63, f = n >> 9;
  int q = l >> 4, col = l & 15;
  int tt, kb, gate;
  if (f < 160)      { tt = f / 10;               kb = f % 10;        gate = 0; }
  else if (f < 320) { int f2 = f - 160; tt = f2 / 10; kb = f2 % 10;  gate = 1; }
  else if (f < 448) { int f3 = f - 320; tt = f3 / 8;  kb = f3 % 8;   gate = 2; }
  else              { int f4 = f - 448; tt = f4 / 2;  kb = 8 + (f4 & 1); gate = 3; }
  int j = (tt & 15) * 16 + col;
  int k = kb * 32 + q * 8 + i;
  float v;
  if (gate == 0)      v = (k < 256) ? w_hh[(0   + j) * 256 + k] : w_ih[(0   + j) * 64 + (k - 256)];
  else if (gate == 1) v = (k < 256) ? w_hh[(256 + j) * 256 + k] : w_ih[(256 + j) * 64 + (k - 256)];
  else if (gate == 2) v = w_hh[(512 + j) * 256 + k];
  else                v = w_ih[(512 + j) * 64 + (k - 256)];
  wb[n] = (_Float16)v;
}

__device__ __forceinline__ float sigm(float v) {
  return __builtin_amdgcn_rcpf(1.0f + __expf(-v));
}
__device__ __forceinline__ float tanh_f(float v) {
  return 1.0f - 2.0f * __builtin_amdgcn_rcpf(1.0f + __expf(2.0f * v));
}

#define MFMA16(a, b, c) __builtin_amdgcn_mfma_f32_16x16x32_f16(a, b, c, 0, 0, 0)
#define FDOT(W, X, A) __builtin_amdgcn_fdot2(__builtin_bit_cast(f16x2, W), \
                                             __builtin_bit_cast(f16x2, X), A, false)

// ------------- R19: 4-way hidden-split recurrence, B fully LDS-resident -------------
// R10-R18 ledger: the 16-block design must move 480 KB of B per CU per step; LDS
// holds 128 KB, the allocator NEVER grants >128 arch regs (8 rounds, 5 mechanisms),
// so >=350 KB streamed from L2/scratch every step -> the ~4800 cyc/step floor.
// Fix the structure instead of fighting the allocator: 64 blocks = 16 groups x 4
// hidden-quarters. A block computes h-cols [qb*64, qb*64+64) for 16 seqs:
// B-slice = 3 gates x 64 cols x 320 K x 2B = 120 KB -> ENTIRELY in LDS. Zero
// restream, zero pins, ~80 VGPR. Per step, blocks exchange their 2 KB h-quarter
// via a parity-double-buffered global HX + monotone device-scope atomic flags
// (skew bounded to 1 step -> parity is race-free; flags monotone -> no reset).
// Per-step/CU: 160 b128 LDS reads (~1920cyc) + GATE + drain/flag + spin/load
// (HD-dump + x-prefetch overlap the spin window) ~= 3300-3800 cyc.
__global__ __launch_bounds__(THR) void gru_kernel(
    const float* __restrict__ x,      // [B, T, I]
    const float* __restrict__ b_ih,   // [768]
    const float* __restrict__ b_hh,   // [768]
    const _Float16* __restrict__ wb,  // packed B fragments
    _Float16* __restrict__ HD,        // [NT][NB][NH] f16 hidden-state dump
    _Float16* __restrict__ HX,        // [2][NB][NH] f16 h exchange (parity)
    int* __restrict__ flags)          // [NGRP*QB] monotone step flags
{
  __shared__ __align__(16) _Float16 H[2][NSEQ][HS];   // 22016 B, double-buffered
  __shared__ __align__(16) _Float16 WB[120 * 512];    // 122880 B: this block's B-slice

  const int tid  = threadIdx.x;     // 0..255
  const int lane = tid & 63;
  const int w    = tid >> 6;        // wave 0..3
  const int q    = lane >> 4;       // quad 0..3
  const int col  = lane & 15;
  const int gidx = blockIdx.x >> 2; // group 0..15
  const int qb   = blockIdx.x & 3;  // hidden quarter 0..3
  const int b0   = gidx * NSEQ;
  const int tt   = qb * 4 + w;      // global col-tile owned by this wave
  const int j    = tt * 16 + col;   // global hidden unit owned in epilogue

  // ---- stage this block's 120 B-frags to LDS (coalesced float4) ----
  // LDS slot = tau*30 + r (tau = tile-in-block 0..3): r<10 -> r-gate kb=r;
  // r<20 -> z-gate kb=r-10; r<28 -> n_h kb=r-20; else i_n s=r-28.
  {
    const float4* src4 = (const float4*)wb;
    float4* dst4 = (float4*)WB;
    #pragma unroll
    for (int it = 0; it < 30; ++it) {
      int d = tid + it * THR;           // 0..7679
      int slot = d >> 6, elem = d & 63;
      int tau = slot / 30, r = slot % 30;
      int gt = qb * 4 + tau;
      int f = (r < 10) ? (gt * 10 + r)
            : (r < 20) ? (160 + gt * 10 + (r - 10))
            : (r < 28) ? (320 + gt * 8 + (r - 20))
                       : (448 + gt * 2 + (r - 28));
      dst4[d] = src4[(size_t)f * 64 + elem];
    }
  }
  // wave's B base: tile tau = w
  const _Float16* wB = WB + (size_t)(w * 30) * 512 + (size_t)lane * 8;

  const float br   = b_ih[j] + b_hh[j];
  const float bz   = b_ih[256 + j] + b_hh[256 + j];
  const float bin_ = b_ih[512 + j];
  const float bhn  = b_hh[512 + j];

  // ---- init: zero H (both buffers), stage x(t=0) ----
  {
    float4* hz = (float4*)H;
    #pragma unroll
    for (int it = 0; it < 6; ++it) {
      int idx = tid + it * THR;
      if (idx < (int)(sizeof(H) / 16)) hz[idx] = float4{0, 0, 0, 0};
    }
  }
  const int r16 = tid >> 4, c4 = (tid & 15) * 4;
  const float* xbase = x + (size_t)(b0 + r16) * (NT * NI) + c4;
  __syncthreads();
  {
    float4 v = *(const float4*)xbase;   // x at t=0
    f16x4 xh; xh[0] = (_Float16)v.x; xh[1] = (_Float16)v.y;
    xh[2] = (_Float16)v.z; xh[3] = (_Float16)v.w;
    *(f16x4*)&H[0][r16][256 + c4] = xh;
  }
  float h0 = 0.0f, h1 = 0.0f, h2 = 0.0f, h3 = 0.0f;
  __syncthreads();

  for (int t = 0; t < NT; ++t) {
    const int cur = t & 1, nxt = cur ^ 1;   // cur also = HX parity for h_t

    // ---- GEMM: A row = seq = col (validated), 30 MFMAs/wave ----
    const _Float16* hrow = &H[cur][col][q * 8];
    floatx4 cR = {0,0,0,0}, cZ = {0,0,0,0}, cN = {0,0,0,0}, cI = {0,0,0,0};
    #pragma unroll
    for (int k = 0; k < 8; ++k) {
      half8 a = *(const half8*)(hrow + k * 32);
      cR = MFMA16(a, *(const half8*)(wB + (size_t)(k)      * 512), cR);
      cZ = MFMA16(a, *(const half8*)(wB + (size_t)(10 + k) * 512), cZ);
      cN = MFMA16(a, *(const half8*)(wB + (size_t)(20 + k) * 512), cN);
    }
    { half8 a = *(const half8*)(hrow + 8 * 32);   // x cols [0,32)
      cR = MFMA16(a, *(const half8*)(wB + (size_t)8  * 512), cR);
      cZ = MFMA16(a, *(const half8*)(wB + (size_t)18 * 512), cZ);
      cI = MFMA16(a, *(const half8*)(wB + (size_t)28 * 512), cI); }
    { half8 a = *(const half8*)(hrow + 9 * 32);   // x cols [32,64)
      cR = MFMA16(a, *(const half8*)(wB + (size_t)9  * 512), cR);
      cZ = MFMA16(a, *(const half8*)(wB + (size_t)19 * 512), cZ);
      cI = MFMA16(a, *(const half8*)(wB + (size_t)29 * 512), cI); }

    // ---- GATE + store own quarter to HX[cur]: lane owns (j, seqs q*4..q*4+3) ----
    _Float16* hxp = HX + ((size_t)cur * NB + b0 + q * 4) * NH + j;
#define GATE(m, hvar) { \
    float rr = sigm(cR[m] + br); \
    float zz = sigm(cZ[m] + bz); \
    float nn = tanh_f(cI[m] + bin_ + rr * (cN[m] + bhn)); \
    hvar = (1.0f - zz) * nn + zz * hvar; \
    hxp[(size_t)(m) * NH] = (_Float16)hvar; }
    GATE(0, h0) GATE(1, h1) GATE(2, h2) GATE(3, h3)
#undef GATE

    // ---- release: all stores visible, then post monotone flag ----
    __threadfence();
    __syncthreads();
    if (tid == 0)
      __hip_atomic_store(&flags[gidx * QB + qb], t + 1,
                         __ATOMIC_RELEASE, __HIP_MEMORY_SCOPE_AGENT);

    // ---- overlap window: HD dump of h_{t-1} (own 64 cols) + x(t+1) prefetch ----
    float4 xv = {0, 0, 0, 0};
    if (t + 1 < NT) xv = *(const float4*)(xbase + (size_t)(t + 1) * NI);
    if (t > 0 && tid < 128) {
      int row = tid >> 3, c8 = tid & 7;
      float4 hv = *(const float4*)&H[cur][row][qb * 64 + c8 * 8];
      *(float4*)(HD + ((size_t)(t - 1) * NB + b0 + row) * NH + qb * 64 + c8 * 8) = hv;
    }

    // ---- acquire: spin on the 3 partner flags ----
    if (tid < QB && tid != qb) {
      while (__hip_atomic_load(&flags[gidx * QB + tid],
                               __ATOMIC_RELAXED, __HIP_MEMORY_SCOPE_AGENT) < t + 1) {}
    }
    __syncthreads();
    __threadfence();

    // ---- gather full h_t from HX[cur] into H[nxt] (incl. own quarter) ----
    {
      const float4* hx4 = (const float4*)(HX + ((size_t)cur * NB + b0) * NH);
      #pragma unroll
      for (int it = 0; it < 2; ++it) {
        int d = tid + it * THR;          // 0..511
        int row = d >> 5, c8 = d & 31;
        *(float4*)&H[nxt][row][c8 * 8] = hx4[(size_t)row * (NH / 8) + c8];
      }
    }
    if (t + 1 < NT) {
      f16x4 xh; xh[0] = (_Float16)xv.x; xh[1] = (_Float16)xv.y;
      xh[2] = (_Float16)xv.z; xh[3] = (_Float16)xv.w;
      *(f16x4*)&H[nxt][r16][256 + c4] = xh;
    }
    __syncthreads();
  }

  // ---- final dump: h_{NT-1} lives in H[0] (NT even), own 64 cols ----
  if (tid < 128) {
    int row = tid >> 3, c8 = tid & 7;
    float4 hv = *(const float4*)&H[0][row][qb * 64 + c8 * 8];
    *(float4*)(HD + ((size_t)(NT - 1) * NB + b0 + row) * NH + qb * 64 + c8 * 8) = hv;
  }
}

// ---------------- epilogue: out[t][b] = HD[t][b][:] . w_out + b_out ----------------
__global__ __launch_bounds__(256) void gru_out_kernel(
    const _Float16* __restrict__ HD, const float* __restrict__ w_out,
    const float* __restrict__ b_out, float* __restrict__ out)
{
  __shared__ __align__(16) _Float16 WL[NH];
  int tid = threadIdx.x;
  WL[tid] = (_Float16)w_out[tid];
  __syncthreads();
  int gid = blockIdx.x * 256 + tid;          // gid = t*NB + b
  const float4* hp = (const float4*)(HD + (size_t)gid * NH);
  const float4* wp = (const float4*)WL;
  float acc = 0.0f;
  #pragma unroll
  for (int i = 0; i < NH / 8; ++i) {
    float4 hv = hp[i];
    float4 wv = wp[i];
    acc = FDOT(hv.x, wv.x, acc);
    acc = FDOT(hv.y, wv.y, acc);
    acc = FDOT(hv.z, wv.z, acc);
    acc = FDOT(hv.w, wv.w, acc);
  }
  out[gid] = acc + b_out[0];
}

extern "C" void kernel_launch(void* const* d_in, const int* in_sizes, int n_in,
                              void* d_out, int out_size, void* d_ws, size_t ws_size,
                              hipStream_t stream) {
  const float* x     = (const float*)d_in[0];
  const float* w_ih  = (const float*)d_in[1];
  const float* w_hh  = (const float*)d_in[2];
  const float* b_ih  = (const float*)d_in[3];
  const float* b_hh  = (const float*)d_in[4];
  const float* w_out = (const float*)d_in[5];
  const float* b_out = (const float*)d_in[6];
  float* out = (float*)d_out;

  _Float16* wb = (_Float16*)d_ws;            // 480 KB packed B fragments
  _Float16* HD = wb + WB_N;                  // 64 MB hidden-state dump
  _Float16* HX = HD + HD_N;                  // 256 KB h exchange (parity-buffered)
  int* flags   = (int*)(HX + HX_N);          // 256 B monotone flags

  gru_prep_kernel<<<(WB_N + 255) / 256, 256, 0, stream>>>(w_ih, w_hh, wb, flags);
  gru_kernel<<<NBLK, THR, 0, stream>>>(x, b_ih, b_hh, wb, HD, HX, flags);
  gru_out_kernel<<<(NT * NB) / 256, 256, 0, stream>>>(HD, w_out, b_out, out);
}

// Round 11
// 1188.136 us; speedup vs baseline: 4.7943x; 4.7943x over previous
//
#include <hip/hip_runtime.h>

typedef _Float16 half8 __attribute__((ext_vector_type(8)));
typedef _Float16 f16x2 __attribute__((ext_vector_type(2)));
typedef _Float16 f16x4 __attribute__((ext_vector_type(4)));
typedef float floatx4 __attribute__((ext_vector_type(4)));

#define NB 256    // batch
#define NT 512    // time
#define NI 64     // input
#define NH 256    // hidden
#define NSEQ 16   // sequences per group
#define QB 4      // hidden quarters (blocks per group)
#define NGRP (NB / NSEQ)     // 16 groups
#define NBLK (NGRP * QB)     // 64 blocks, 1 CU each
#define THR 256              // 4 waves
#define HS 344               // H row stride in f16 (validated bank pattern)

// B-fragment pack (VALIDATED R9/R10): 480 frags x 64 lanes x 8 f16.
// Cols: [0,256)=r, [256,512)=z, [512,768)=h_n, [768,1024)=i_n. K: [0,256)=h, [256,320)=x.
// frag f: r: tt*10+kb; z: 160+tt*10+kb; h_n: 320+tt*8+kb (kb<8); i_n: 448+tt*2+(kb-8).
// wb[f*512 + lane*8 + i] = W[k = kb*32 + (lane>>4)*8 + i][n = tt*16 + (lane&15)]
#define WB_N (480 * 512)
#define HD_N ((size_t)NT * NB * NH)
#define HX_N ((size_t)2 * NB * NH)   // parity-double-buffered h exchange (f16)

__global__ __launch_bounds__(256) void gru_prep_kernel(
    const float* __restrict__ w_ih, const float* __restrict__ w_hh,
    _Float16* __restrict__ wb, int* __restrict__ flags)
{
  if (blockIdx.x == 0 && threadIdx.x < NBLK) flags[threadIdx.x * 32] = 0;  // reset (padded)
  int n = blockIdx.x * 256 + threadIdx.x;
  if (n >= WB_N) return;
  int i = n & 7, l = (n >> 3) & 63, f = n >> 9;
  int q = l >> 4, col = l & 15;
  int tt, kb, gate;
  if (f < 160)      { tt = f / 10;               kb = f % 10;        gate = 0; }
  else if (f < 320) { int f2 = f - 160; tt = f2 / 10; kb = f2 % 10;  gate = 1; }
  else if (f < 448) { int f3 = f - 320; tt = f3 / 8;  kb = f3 % 8;   gate = 2; }
  else              { int f4 = f - 448; tt = f4 / 2;  kb = 8 + (f4 & 1); gate = 3; }
  int j = (tt & 15) * 16 + col;
  int k = kb * 32 + q * 8 + i;
  float v;
  if (gate == 0)      v = (k < 256) ? w_hh[(0   + j) * 256 + k] : w_ih[(0   + j) * 64 + (k - 256)];
  else if (gate == 1) v = (k < 256) ? w_hh[(256 + j) * 256 + k] : w_ih[(256 + j) * 64 + (k - 256)];
  else if (gate == 2) v = w_hh[(512 + j) * 256 + k];
  else                v = w_ih[(512 + j) * 64 + (k - 256)];
  wb[n] = (_Float16)v;
}

__device__ __forceinline__ float sigm(float v) {
  return __builtin_amdgcn_rcpf(1.0f + __expf(-v));
}
__device__ __forceinline__ float tanh_f(float v) {
  return 1.0f - 2.0f * __builtin_amdgcn_rcpf(1.0f + __expf(2.0f * v));
}

#define MFMA16(a, b, c) __builtin_amdgcn_mfma_f32_16x16x32_f16(a, b, c, 0, 0, 0)
#define FDOT(W, X, A) __builtin_amdgcn_fdot2(__builtin_bit_cast(f16x2, W), \
                                             __builtin_bit_cast(f16x2, X), A, false)

// Relaxed agent-scope atomics = global_store/load_dwordx2 with sc1 (device
// coherence point, Infinity-Cache-served), NO buffer_wbl2/buffer_inv emitted.
typedef unsigned long long u64;
__device__ __forceinline__ void hx_store8(u64* p, u64 v) {
  __hip_atomic_store(p, v, __ATOMIC_RELAXED, __HIP_MEMORY_SCOPE_AGENT);
}
__device__ __forceinline__ u64 hx_load8(const u64* p) {
  return __hip_atomic_load(p, __ATOMIC_RELAXED, __HIP_MEMORY_SCOPE_AGENT);
}

// ------------- R21: R20's design, exchange via relaxed __hip_atomic_* -------------
// R20 failed to COMPILE (clang can't take a 64-bit pointer under "v" in inline
// asm). Same plan, builtin form: relaxed agent atomics give the sc1 cache-bypass
// path without fences; ordering data->flag via explicit s_waitcnt vmcnt(0)
// (zero-operand asm, compiles). Structure unchanged from R19/R20 (numerically
// validated in R19): 64 blocks = 16 groups x 4 quarters, 120 KB B fully in LDS,
// parity HX + monotone flags (skew<=1 proof in R19 notes).
__global__ __launch_bounds__(THR) void gru_kernel(
    const float* __restrict__ x,      // [B, T, I]
    const float* __restrict__ b_ih,   // [768]
    const float* __restrict__ b_hh,   // [768]
    const _Float16* __restrict__ wb,  // packed B fragments
    _Float16* __restrict__ HD,        // [NT][NB][NH] f16 hidden-state dump
    _Float16* __restrict__ HX,        // [2][NB][NH] f16 h exchange (parity)
    int* __restrict__ flags)          // [NBLK*32] monotone step flags (padded)
{
  __shared__ __align__(16) _Float16 H[2][NSEQ][HS];   // 22016 B, double-buffered
  __shared__ __align__(16) _Float16 WB[120 * 512];    // 122880 B: this block's B-slice

  const int tid  = threadIdx.x;     // 0..255
  const int lane = tid & 63;
  const int w    = tid >> 6;        // wave 0..3
  const int q    = lane >> 4;       // quad 0..3
  const int col  = lane & 15;
  const int gidx = blockIdx.x & 15; // group 0..15  (same-XCD partner mapping)
  const int qb   = blockIdx.x >> 4; // hidden quarter 0..3
  const int b0   = gidx * NSEQ;
  const int tt   = qb * 4 + w;      // global col-tile owned by this wave
  const int j    = tt * 16 + col;   // global hidden unit owned in epilogue

  // ---- stage this block's 120 B-frags to LDS (coalesced float4) ----
  {
    const float4* src4 = (const float4*)wb;
    float4* dst4 = (float4*)WB;
    #pragma unroll
    for (int it = 0; it < 30; ++it) {
      int d = tid + it * THR;           // 0..7679
      int slot = d >> 6, elem = d & 63;
      int tau = slot / 30, r = slot % 30;
      int gt = qb * 4 + tau;
      int f = (r < 10) ? (gt * 10 + r)
            : (r < 20) ? (160 + gt * 10 + (r - 10))
            : (r < 28) ? (320 + gt * 8 + (r - 20))
                       : (448 + gt * 2 + (r - 28));
      dst4[d] = src4[(size_t)f * 64 + elem];
    }
  }
  const _Float16* wB = WB + (size_t)(w * 30) * 512 + (size_t)lane * 8;

  const float br   = b_ih[j] + b_hh[j];
  const float bz   = b_ih[256 + j] + b_hh[256 + j];
  const float bin_ = b_ih[512 + j];
  const float bhn  = b_hh[512 + j];

  // ---- init: zero H (both buffers), stage x(t=0) ----
  {
    float4* hz = (float4*)H;
    #pragma unroll
    for (int it = 0; it < 6; ++it) {
      int idx = tid + it * THR;
      if (idx < (int)(sizeof(H) / 16)) hz[idx] = float4{0, 0, 0, 0};
    }
  }
  const int r16 = tid >> 4, c4 = (tid & 15) * 4;
  const float* xbase = x + (size_t)(b0 + r16) * (NT * NI) + c4;
  __syncthreads();
  {
    float4 v = *(const float4*)xbase;   // x at t=0
    f16x4 xh; xh[0] = (_Float16)v.x; xh[1] = (_Float16)v.y;
    xh[2] = (_Float16)v.z; xh[3] = (_Float16)v.w;
    *(f16x4*)&H[0][r16][256 + c4] = xh;
  }
  float h0 = 0.0f, h1 = 0.0f, h2 = 0.0f, h3 = 0.0f;
  __syncthreads();

  for (int t = 0; t < NT; ++t) {
    const int cur = t & 1, nxt = cur ^ 1;   // cur = HX parity for h_t

    // ---- GEMM: A row = seq = col (validated), 30 MFMAs/wave ----
    const _Float16* hrow = &H[cur][col][q * 8];
    floatx4 cR = {0,0,0,0}, cZ = {0,0,0,0}, cN = {0,0,0,0}, cI = {0,0,0,0};
    #pragma unroll
    for (int k = 0; k < 8; ++k) {
      half8 a = *(const half8*)(hrow + k * 32);
      cR = MFMA16(a, *(const half8*)(wB + (size_t)(k)      * 512), cR);
      cZ = MFMA16(a, *(const half8*)(wB + (size_t)(10 + k) * 512), cZ);
      cN = MFMA16(a, *(const half8*)(wB + (size_t)(20 + k) * 512), cN);
    }
    { half8 a = *(const half8*)(hrow + 8 * 32);   // x cols [0,32)
      cR = MFMA16(a, *(const half8*)(wB + (size_t)8  * 512), cR);
      cZ = MFMA16(a, *(const half8*)(wB + (size_t)18 * 512), cZ);
      cI = MFMA16(a, *(const half8*)(wB + (size_t)28 * 512), cI); }
    { half8 a = *(const half8*)(hrow + 9 * 32);   // x cols [32,64)
      cR = MFMA16(a, *(const half8*)(wB + (size_t)9  * 512), cR);
      cZ = MFMA16(a, *(const half8*)(wB + (size_t)19 * 512), cZ);
      cI = MFMA16(a, *(const half8*)(wB + (size_t)29 * 512), cI); }

    // ---- GATE -> H[nxt] own cols (LDS): lane owns (j, seqs q*4..q*4+3) ----
#define GATE(m, hvar) { \
    float rr = sigm(cR[m] + br); \
    float zz = sigm(cZ[m] + bz); \
    float nn = tanh_f(cI[m] + bin_ + rr * (cN[m] + bhn)); \
    hvar = (1.0f - zz) * nn + zz * hvar; \
    H[nxt][q * 4 + (m)][j] = (_Float16)hvar; }
    GATE(0, h0) GATE(1, h1) GATE(2, h2) GATE(3, h3)
#undef GATE
    __syncthreads();   // own-quarter of H[nxt] complete

    if (t + 1 < NT) {
      // ---- copy-out own quarter to HX[cur]: 256 thr x 8B sc1 stores ----
      {
        u64 v = *(const u64*)&H[nxt][r16][qb * 64 + (tid & 15) * 4];
        hx_store8((u64*)(HX + ((size_t)cur * NB + b0 + r16) * NH + qb * 64 + (tid & 15) * 4), v);
      }
      asm volatile("s_waitcnt vmcnt(0)" ::: "memory");
      __syncthreads();
      if (tid == 0) atomicAdd(&flags[(gidx * QB + qb) * 32], 1);   // posts value t+1

      // ---- overlap window: HD dump of h_{t-1} (own cols) + x(t+1) prefetch ----
      float4 xv = *(const float4*)(xbase + (size_t)(t + 1) * NI);
      if (t > 0 && tid < 128) {
        int row = tid >> 3, c8 = tid & 7;
        float4 hv = *(const float4*)&H[cur][row][qb * 64 + c8 * 8];
        *(float4*)(HD + ((size_t)(t - 1) * NB + b0 + row) * NH + qb * 64 + c8 * 8) = hv;
      }

      // ---- poll partner flags (device-coherent RMW read; backoff) ----
      if (tid < QB && tid != qb) {
        while (atomicAdd(&flags[(gidx * QB + tid) * 32], 0) < t + 1)
          __builtin_amdgcn_s_sleep(2);
      }
      __syncthreads();

      // ---- gather 3 partner quarters (6 KB) via sc1 loads -> H[nxt] ----
      {
        const u64* hxb = (const u64*)(HX + (size_t)cur * NB * NH);
        int pq0i = 0, pq1i = 1, pq2i = 2;
        int pq0 = pq0i + (pq0i >= qb ? 1 : 0);
        int pq1 = pq1i + (pq1i >= qb ? 1 : 0);
        int pq2 = pq2i + (pq2i >= qb ? 1 : 0);
        int row = tid >> 4, ca = tid & 15;
        size_t rb = (size_t)(b0 + row) * (NH / 4);   // u64 units per row = 64
        u64 v0 = hx_load8(hxb + rb + pq0 * 16 + ca);
        u64 v1 = hx_load8(hxb + rb + pq1 * 16 + ca);
        u64 v2 = hx_load8(hxb + rb + pq2 * 16 + ca);
        *(u64*)&H[nxt][row][pq0 * 64 + ca * 4] = v0;
        *(u64*)&H[nxt][row][pq1 * 64 + ca * 4] = v1;
        *(u64*)&H[nxt][row][pq2 * 64 + ca * 4] = v2;
      }
      // ---- x(t+1) into H[nxt] ----
      {
        f16x4 xh; xh[0] = (_Float16)xv.x; xh[1] = (_Float16)xv.y;
        xh[2] = (_Float16)xv.z; xh[3] = (_Float16)xv.w;
        *(f16x4*)&H[nxt][r16][256 + c4] = xh;
      }
      __syncthreads();
    } else {
      // last step: HD dump of h_{t-1} only; h_{NT-1} handled after loop
      if (tid < 128) {
        int row = tid >> 3, c8 = tid & 7;
        float4 hv = *(const float4*)&H[cur][row][qb * 64 + c8 * 8];
        *(float4*)(HD + ((size_t)(t - 1) * NB + b0 + row) * NH + qb * 64 + c8 * 8) = hv;
      }
    }
  }

  // ---- final dump: h_{NT-1} lives in H[0] (NT even), own 64 cols ----
  if (tid < 128) {
    int row = tid >> 3, c8 = tid & 7;
    float4 hv = *(const float4*)&H[0][row][qb * 64 + c8 * 8];
    *(float4*)(HD + ((size_t)(NT - 1) * NB + b0 + row) * NH + qb * 64 + c8 * 8) = hv;
  }
}

// ---------------- epilogue: out[t][b] = HD[t][b][:] . w_out + b_out ----------------
__global__ __launch_bounds__(256) void gru_out_kernel(
    const _Float16* __restrict__ HD, const float* __restrict__ w_out,
    const float* __restrict__ b_out, float* __restrict__ out)
{
  __shared__ __align__(16) _Float16 WL[NH];
  int tid = threadIdx.x;
  WL[tid] = (_Float16)w_out[tid];
  __syncthreads();
  int gid = blockIdx.x * 256 + tid;          // gid = t*NB + b
  const float4* hp = (const float4*)(HD + (size_t)gid * NH);
  const float4* wp = (const float4*)WL;
  float acc = 0.0f;
  #pragma unroll
  for (int i = 0; i < NH / 8; ++i) {
    float4 hv = hp[i];
    float4 wv = wp[i];
    acc = FDOT(hv.x, wv.x, acc);
    acc = FDOT(hv.y, wv.y, acc);
    acc = FDOT(hv.z, wv.z, acc);
    acc = FDOT(hv.w, wv.w, acc);
  }
  out[gid] = acc + b_out[0];
}

extern "C" void kernel_launch(void* const* d_in, const int* in_sizes, int n_in,
                              void* d_out, int out_size, void* d_ws, size_t ws_size,
                              hipStream_t stream) {
  const float* x     = (const float*)d_in[0];
  const float* w_ih  = (const float*)d_in[1];
  const float* w_hh  = (const float*)d_in[2];
  const float* b_ih  = (const float*)d_in[3];
  const float* b_hh  = (const float*)d_in[4];
  const float* w_out = (const float*)d_in[5];
  const float* b_out = (const float*)d_in[6];
  float* out = (float*)d_out;

  _Float16* wb = (_Float16*)d_ws;            // 480 KB packed B fragments
  _Float16* HD = wb + WB_N;                  // 64 MB hidden-state dump
  _Float16* HX = HD + HD_N;                  // 256 KB h exchange (parity-buffered)
  int* flags   = (int*)(HX + HX_N);          // 8 KB padded monotone flags

  gru_prep_kernel<<<(WB_N + 255) / 256, 256, 0, stream>>>(w_ih, w_hh, wb, flags);
  gru_kernel<<<NBLK, THR, 0, stream>>>(x, b_ih, b_hh, wb, HD, HX, flags);
  gru_out_kernel<<<(NT * NB) / 256, 256, 0, stream>>>(HD, w_out, b_out, out);
}